// Round 17
// baseline (389.360 us; speedup 1.0000x reference)
//
#include <hip/hip_runtime.h>
#include <hip/hip_bf16.h>
#include <cstdint>

#define B_ 2
#define T_ 2048
#define D_ 512
#define H_ 8
#define DK_ 64
#define TQ_ 4                 // rows per block
#define NTL_ (T_ / TQ_)       // 512 tiles per batch
#define M_ (B_ * T_)          // 4096

#define SSC_ 8192.0f          // score fixed-point scale (i16)
#define S2_  (SSC_ * SSC_)    // scaled Newton target

// ---------------- GEMM: C[M,N] = A[M,K] @ W[K,N] + bias[N] ----------------
__global__ __launch_bounds__(256) void gemm_bias_kernel(
    const float* __restrict__ A, const float* __restrict__ W,
    const float* __restrict__ bias, float* __restrict__ C,
    int M, int N, int K)
{
  __shared__ float As[32][68];  // transposed A tile: As[k][m]
  __shared__ float Bs[32][68];
  const int bm = blockIdx.y * 64;
  const int bn = blockIdx.x * 64;
  const int tid = threadIdx.x;
  const int tx = tid & 15, ty = tid >> 4;
  float acc[4][4] = {};
  for (int k0 = 0; k0 < K; k0 += 32) {
    {
      const int r = tid >> 2;           // 0..63
      const int c = (tid & 3) << 2;     // 0,4,8,12
      const float4 a0 = *reinterpret_cast<const float4*>(&A[(size_t)(bm + r) * K + k0 + c]);
      const float4 a1 = *reinterpret_cast<const float4*>(&A[(size_t)(bm + r) * K + k0 + 16 + c]);
      As[c + 0][r] = a0.x;  As[c + 1][r] = a0.y;  As[c + 2][r] = a0.z;  As[c + 3][r] = a0.w;
      As[c + 16][r] = a1.x; As[c + 17][r] = a1.y; As[c + 18][r] = a1.z; As[c + 19][r] = a1.w;
    }
    {
      const int r = tid >> 4;           // 0..15
      const int c = (tid & 15) << 2;    // 0..60
      *reinterpret_cast<float4*>(&Bs[r][c]) =
          *reinterpret_cast<const float4*>(&W[(size_t)(k0 + r) * N + bn + c]);
      *reinterpret_cast<float4*>(&Bs[r + 16][c]) =
          *reinterpret_cast<const float4*>(&W[(size_t)(k0 + 16 + r) * N + bn + c]);
    }
    __syncthreads();
#pragma unroll
    for (int kk = 0; kk < 32; ++kk) {
      const float4 av = *reinterpret_cast<const float4*>(&As[kk][ty * 4]);
      const float4 bv = *reinterpret_cast<const float4*>(&Bs[kk][tx * 4]);
      acc[0][0] = fmaf(av.x, bv.x, acc[0][0]); acc[0][1] = fmaf(av.x, bv.y, acc[0][1]);
      acc[0][2] = fmaf(av.x, bv.z, acc[0][2]); acc[0][3] = fmaf(av.x, bv.w, acc[0][3]);
      acc[1][0] = fmaf(av.y, bv.x, acc[1][0]); acc[1][1] = fmaf(av.y, bv.y, acc[1][1]);
      acc[1][2] = fmaf(av.y, bv.z, acc[1][2]); acc[1][3] = fmaf(av.y, bv.w, acc[1][3]);
      acc[2][0] = fmaf(av.z, bv.x, acc[2][0]); acc[2][1] = fmaf(av.z, bv.y, acc[2][1]);
      acc[2][2] = fmaf(av.z, bv.z, acc[2][2]); acc[2][3] = fmaf(av.z, bv.w, acc[2][3]);
      acc[3][0] = fmaf(av.w, bv.x, acc[3][0]); acc[3][1] = fmaf(av.w, bv.y, acc[3][1]);
      acc[3][2] = fmaf(av.w, bv.z, acc[3][2]); acc[3][3] = fmaf(av.w, bv.w, acc[3][3]);
    }
    __syncthreads();
  }
#pragma unroll
  for (int i = 0; i < 4; ++i) {
    const int row = bm + ty * 4 + i;
#pragma unroll
    for (int j = 0; j < 4; ++j) {
      const int col = bn + tx * 4 + j;
      C[(size_t)row * N + col] = acc[i][j] + bias[col];
    }
  }
}

// Same GEMM but writes C TRANSPOSED: Ct[N][M].
__global__ __launch_bounds__(256) void gemm_bias_kernelT(
    const float* __restrict__ A, const float* __restrict__ W,
    const float* __restrict__ bias, float* __restrict__ Ct,
    int M, int N, int K)
{
  __shared__ float As[32][68];
  __shared__ float Bs[32][68];
  const int bm = blockIdx.y * 64;
  const int bn = blockIdx.x * 64;
  const int tid = threadIdx.x;
  const int tx = tid & 15, ty = tid >> 4;
  float acc[4][4] = {};
  for (int k0 = 0; k0 < K; k0 += 32) {
    {
      const int r = tid >> 2;
      const int c = (tid & 3) << 2;
      const float4 a0 = *reinterpret_cast<const float4*>(&A[(size_t)(bm + r) * K + k0 + c]);
      const float4 a1 = *reinterpret_cast<const float4*>(&A[(size_t)(bm + r) * K + k0 + 16 + c]);
      As[c + 0][r] = a0.x;  As[c + 1][r] = a0.y;  As[c + 2][r] = a0.z;  As[c + 3][r] = a0.w;
      As[c + 16][r] = a1.x; As[c + 17][r] = a1.y; As[c + 18][r] = a1.z; As[c + 19][r] = a1.w;
    }
    {
      const int r = tid >> 4;
      const int c = (tid & 15) << 2;
      *reinterpret_cast<float4*>(&Bs[r][c]) =
          *reinterpret_cast<const float4*>(&W[(size_t)(k0 + r) * N + bn + c]);
      *reinterpret_cast<float4*>(&Bs[r + 16][c]) =
          *reinterpret_cast<const float4*>(&W[(size_t)(k0 + 16 + r) * N + bn + c]);
    }
    __syncthreads();
#pragma unroll
    for (int kk = 0; kk < 32; ++kk) {
      const float4 av = *reinterpret_cast<const float4*>(&As[kk][ty * 4]);
      const float4 bv = *reinterpret_cast<const float4*>(&Bs[kk][tx * 4]);
      acc[0][0] = fmaf(av.x, bv.x, acc[0][0]); acc[0][1] = fmaf(av.x, bv.y, acc[0][1]);
      acc[0][2] = fmaf(av.x, bv.z, acc[0][2]); acc[0][3] = fmaf(av.x, bv.w, acc[0][3]);
      acc[1][0] = fmaf(av.y, bv.x, acc[1][0]); acc[1][1] = fmaf(av.y, bv.y, acc[1][1]);
      acc[1][2] = fmaf(av.y, bv.z, acc[1][2]); acc[1][3] = fmaf(av.y, bv.w, acc[1][3]);
      acc[2][0] = fmaf(av.z, bv.x, acc[2][0]); acc[2][1] = fmaf(av.z, bv.y, acc[2][1]);
      acc[2][2] = fmaf(av.z, bv.z, acc[2][2]); acc[2][3] = fmaf(av.z, bv.w, acc[2][3]);
      acc[3][0] = fmaf(av.w, bv.x, acc[3][0]); acc[3][1] = fmaf(av.w, bv.y, acc[3][1]);
      acc[3][2] = fmaf(av.w, bv.z, acc[3][2]); acc[3][3] = fmaf(av.w, bv.w, acc[3][3]);
    }
    __syncthreads();
  }
#pragma unroll
  for (int j = 0; j < 4; ++j) {
    const int col = bn + tx * 4 + j;
    const float bb = bias[col];
    const float4 v = make_float4(acc[0][j] + bb, acc[1][j] + bb, acc[2][j] + bb, acc[3][j] + bb);
    *reinterpret_cast<float4*>(&Ct[(size_t)col * M + bm + ty * 4]) = v;
  }
}

// ---------------- V_combined = mean over heads of V ----------------
__global__ __launch_bounds__(256) void vcombine_kernel(const float* __restrict__ V,
                                                       float* __restrict__ Vc)
{
  const int idx = blockIdx.x * 256 + threadIdx.x;
  if (idx >= M_ * DK_) return;
  const int row = idx >> 6, d = idx & 63;
  float s = 0.f;
#pragma unroll
  for (int h = 0; h < H_; ++h) s += V[(size_t)row * D_ + h * DK_ + d];
  Vc[idx] = s * 0.125f;
}

// ---------------- zero-fill wavg ----------------
__global__ __launch_bounds__(256) void zero_kernel(float4* __restrict__ p, int n4)
{
  const int stride = gridDim.x * 256;
  const float4 z = make_float4(0.f, 0.f, 0.f, 0.f);
  for (int i = blockIdx.x * 256 + threadIdx.x; i < n4; i += stride) p[i] = z;
}

// ---------------- scores + exact entmax + fused sparse PV ----------------
// Score phase uses the CLAMPED form (s0 = min(tid*4+c, nS-4)) under a SCALAR
// guard (c < nS): keeps every Q address wave-uniform so Q loads stay on the
// scalar (SMEM) pipe. Per-lane guards here demote Q to vector loads (-80us, r16).
__global__ __launch_bounds__(256, 6)
void attn_kernel(
    const float* __restrict__ Qg, const float* __restrict__ Kt,
    const float* __restrict__ Vc, float* __restrict__ wavg,
    float* __restrict__ AOh)
{
  __shared__ short ssc[TQ_][T_];            // 16 KB

  const int tid = threadIdx.x;
  const int bid = blockIdx.x;
  const int h = bid >> 10;                  // 0..7
  const int b = (bid >> 9) & 1;
  const int tile = (NTL_ - 1) - (bid & 511);  // heavy tiles first
  const int t0 = tile * TQ_;
  const int nS = t0 + TQ_;
  const int wave = __builtin_amdgcn_readfirstlane(tid >> 6);  // 0..3 (SGPR)
  const int lane = tid & 63;

  // ---- scores -> i16 * 8192 ----
  {
    const float* Qp = &Qg[(size_t)(b * T_ + t0) * D_ + h * DK_];  // block-uniform
#pragma unroll 1
    for (int c = 0; c < T_; c += 1024) {
      if (c < nS) {                              // SCALAR guard
        const int s0 = min(tid * 4 + c, nS - 4); // clamp: duplicates write same values
        const float* Ktp = &Kt[(size_t)(h * DK_) * M_ + b * T_ + s0];
        float4 a[TQ_];
#pragma unroll
        for (int r = 0; r < TQ_; ++r) a[r] = make_float4(0.f, 0.f, 0.f, 0.f);
#pragma unroll 2
        for (int d4 = 0; d4 < 16; ++d4) {
          const float4 k0 = *reinterpret_cast<const float4*>(Ktp + (size_t)(d4 * 4 + 0) * M_);
          const float4 k1 = *reinterpret_cast<const float4*>(Ktp + (size_t)(d4 * 4 + 1) * M_);
          const float4 k2 = *reinterpret_cast<const float4*>(Ktp + (size_t)(d4 * 4 + 2) * M_);
          const float4 k3 = *reinterpret_cast<const float4*>(Ktp + (size_t)(d4 * 4 + 3) * M_);
#pragma unroll
          for (int r = 0; r < TQ_; ++r) {
            const float q0 = Qp[r * D_ + d4 * 4 + 0];  // scalar loads (uniform)
            const float q1 = Qp[r * D_ + d4 * 4 + 1];
            const float q2 = Qp[r * D_ + d4 * 4 + 2];
            const float q3 = Qp[r * D_ + d4 * 4 + 3];
            a[r].x = fmaf(q0, k0.x, a[r].x); a[r].y = fmaf(q0, k0.y, a[r].y);
            a[r].z = fmaf(q0, k0.z, a[r].z); a[r].w = fmaf(q0, k0.w, a[r].w);
            a[r].x = fmaf(q1, k1.x, a[r].x); a[r].y = fmaf(q1, k1.y, a[r].y);
            a[r].z = fmaf(q1, k1.z, a[r].z); a[r].w = fmaf(q1, k1.w, a[r].w);
            a[r].x = fmaf(q2, k2.x, a[r].x); a[r].y = fmaf(q2, k2.y, a[r].y);
            a[r].z = fmaf(q2, k2.z, a[r].z); a[r].w = fmaf(q2, k2.w, a[r].w);
            a[r].x = fmaf(q3, k3.x, a[r].x); a[r].y = fmaf(q3, k3.y, a[r].y);
            a[r].z = fmaf(q3, k3.z, a[r].z); a[r].w = fmaf(q3, k3.w, a[r].w);
          }
        }
        // z_scaled = dot * 0.0625 * 8192 = dot * 512
#pragma unroll
        for (int r = 0; r < TQ_; ++r) {
          const int i0 = __float2int_rn(fminf(fmaxf(a[r].x * 512.f, -32000.f), 32000.f));
          const int i1 = __float2int_rn(fminf(fmaxf(a[r].y * 512.f, -32000.f), 32000.f));
          const int i2 = __float2int_rn(fminf(fmaxf(a[r].z * 512.f, -32000.f), 32000.f));
          const int i3 = __float2int_rn(fminf(fmaxf(a[r].w * 512.f, -32000.f), 32000.f));
          short4 st; st.x = (short)i0; st.y = (short)i1; st.z = (short)i2; st.w = (short)i3;
          *reinterpret_cast<short4*>(&ssc[r][s0]) = st;
        }
      }
    }
  }
  __syncthreads();

  // ---- entmax on row t0+wave (exact, register-resident) ----
  const int t = t0 + wave;
  const int n = t + 1;                      // SGPR support size
  float srow[32];                           // s = j*512 + lane*8 + q

#pragma unroll
  for (int j = 0; j < 4; ++j) {
    if (j * 512 < n) {                      // scalar guard
      const uint4 pk = *reinterpret_cast<const uint4*>(&ssc[wave][j * 512 + lane * 8]);
      const unsigned pw[4] = {pk.x, pk.y, pk.z, pk.w};
#pragma unroll
      for (int q = 0; q < 4; ++q) {
        const int s_lo = j * 512 + lane * 8 + q * 2;
        const float lo = (float)((int)(short)(pw[q] & 0xffffu));
        const float hi = (float)((int)pw[q] >> 16);
        srow[j * 8 + q * 2 + 0] = (s_lo + 0 < n) ? lo : -1e30f;
        srow[j * 8 + q * 2 + 1] = (s_lo + 1 < n) ? hi : -1e30f;
      }
    } else {
#pragma unroll
      for (int q = 0; q < 8; ++q) srow[j * 8 + q] = -1e30f;
    }
  }
  asm volatile("" ::: "memory");            // keep srow in registers

  float mx = -1e30f;
#pragma unroll
  for (int i = 0; i < 32; ++i) mx = fmaxf(mx, srow[i]);
#pragma unroll
  for (int m = 32; m >= 1; m >>= 1) mx = fmaxf(mx, __shfl_xor(mx, m, 64));

  float tau = mx - SSC_;                    // f(tau0) >= 0
#pragma unroll 1
  for (int it = 0; it < 12; ++it) {
    float s1 = 0.f, s2 = 0.f, cn = 0.f;
#pragma unroll
    for (int j = 0; j < 4; ++j) {
      if (j * 512 < n) {
#pragma unroll
        for (int q = 0; q < 8; ++q) {
          const float u = fmaxf(srow[j * 8 + q] - tau, 0.f);
          s1 += u;
          s2 = fmaf(u, u, s2);
          cn += (u > 0.f) ? 1.f : 0.f;
        }
      }
    }
#pragma unroll
    for (int m = 32; m >= 1; m >>= 1) {
      s1 += __shfl_xor(s1, m, 64);
      s2 += __shfl_xor(s2, m, 64);
    }
    if (fabsf(s2 - S2_) < 672.f) break;     // 1e-5 relative
    if (it < 3) {
#pragma unroll
      for (int m = 32; m >= 1; m >>= 1) cn += __shfl_xor(cn, m, 64);
      const float kf = fmaxf(cn, 1.f);
      const float mu = tau + s1 / kf;
      const float ss = s2 - s1 * s1 / kf;
      tau = mu - sqrtf(fmaxf((S2_ - ss) / kf, 0.f));  // exact tau on current support
    } else {
      tau += (s2 - S2_) / fmaxf(2.f * s1, 1e-6f);     // Newton
    }
  }
  tau = fminf(tau, mx - 1.f);

  // ---- scatter weights into wavg AND accumulate PV over nonzeros ----
  const float wconv = 0.125f / (SSC_ * SSC_);
  float* const wrow = &wavg[(size_t)(b * T_ + t) * T_];
  const float* const vb = &Vc[(size_t)(b * T_) * DK_ + lane];
  float pv = 0.f;
#pragma unroll
  for (int j = 0; j < 4; ++j) {
    if (j * 512 < n) {                      // scalar guard
#pragma unroll
      for (int q = 0; q < 8; ++q) {
        const float u = fmaxf(srow[j * 8 + q] - tau, 0.f);
        const float w2 = u * u;             // scaled weight (u/8192)^2 * S2_
        unsigned long long mask = __ballot(w2 > 0.f);
        if (mask) {
          if (w2 > 0.f) {
            atomicAdd(&wrow[j * 512 + lane * 8 + q], w2 * wconv);
          }
          // wave-uniform walk of nonzero lanes: one coalesced Vc row per nonzero
          while (mask) {
            const int l = (int)__ffsll((unsigned long long)mask) - 1;
            mask &= mask - 1;
            const float wl = __shfl(w2, l, 64);
            const int sl = j * 512 + l * 8 + q;
            pv = fmaf(wl, vb[(size_t)sl * DK_], pv);
          }
        }
      }
    }
  }
  // per-head PV (unique writer): AOh[h][b*T+t][lane]
  AOh[((size_t)h * M_ + b * T_ + t) * DK_ + lane] = pv * wconv;
}

// ---------------- AO = sum over heads of AOh ----------------
__global__ __launch_bounds__(256) void aoreduce_kernel(
    const float* __restrict__ AOh, float* __restrict__ AO)
{
  const int idx = blockIdx.x * 256 + threadIdx.x;   // over M_*DK_
  if (idx >= M_ * DK_) return;
  float s = 0.f;
#pragma unroll
  for (int h = 0; h < H_; ++h) s += AOh[(size_t)h * M_ * DK_ + idx];
  AO[idx] = s;
}

extern "C" void kernel_launch(void* const* d_in, const int* in_sizes, int n_in,
                              void* d_out, int out_size, void* d_ws, size_t ws_size,
                              hipStream_t stream)
{
  const float* x  = (const float*)d_in[0];
  const float* Wq = (const float*)d_in[1];
  const float* bq = (const float*)d_in[2];
  const float* Wk = (const float*)d_in[3];
  const float* bk = (const float*)d_in[4];
  const float* Wv = (const float*)d_in[5];
  const float* bv = (const float*)d_in[6];
  const float* Wo = (const float*)d_in[7];
  const float* bo = (const float*)d_in[8];
  float* out = (float*)d_out;
  float* ws  = (float*)d_ws;

  float* Q   = ws;                        // [M,512]
  float* Kt  = Q + (size_t)M_ * D_;       // [512,M]
  float* V   = Kt + (size_t)D_ * M_;      // [M,512]; dead after vcombine
  float* Vc  = V + (size_t)M_ * D_;       // [M,64]
  float* AO  = Vc + (size_t)M_ * DK_;     // [M,64]
  float* AOh = V;                         // reuse V: [H][M][64] = 8.4 MB (== V size)

  float* out1 = out;                    // [B,T,D]
  float* wavg = out + (size_t)M_ * D_;  // [B,T,T]

  const dim3 gp(D_ / 64, M_ / 64);  // (8, 64)
  gemm_bias_kernel <<<gp, 256, 0, stream>>>(x, Wq, bq, Q,  M_, D_, D_);
  gemm_bias_kernelT<<<gp, 256, 0, stream>>>(x, Wk, bk, Kt, M_, D_, D_);
  gemm_bias_kernel <<<gp, 256, 0, stream>>>(x, Wv, bv, V,  M_, D_, D_);
  vcombine_kernel<<<(M_ * DK_ + 255) / 256, 256, 0, stream>>>(V, Vc);

  zero_kernel<<<2048, 256, 0, stream>>>(reinterpret_cast<float4*>(wavg),
                                        (int)((size_t)B_ * T_ * T_ / 4));

  attn_kernel<<<H_ * B_ * NTL_, 256, 0, stream>>>(Q, Kt, Vc, wavg, AOh);
  aoreduce_kernel<<<(M_ * DK_ + 255) / 256, 256, 0, stream>>>(AOh, AO);
  gemm_bias_kernel<<<gp, 256, 0, stream>>>(AO, Wo, bo, out1, M_, D_, DK_);
}